// Round 2
// baseline (281.543 us; speedup 1.0000x reference)
//
#include <hip/hip_runtime.h>
#include <hip/hip_bf16.h>

// A3TGCN reduced form (H0==0 each period => R-gate dead, periods independent):
//   Xagg = A_hat @ x            (one sparse pass, 32 cols = F_IN*PERIODS)
//   per node/period: Z=sigmoid(u@Mz+cz), T=tanh(u@Mh+ch), Hacc += p_t*(1-Z)*T
//   out = relu(Hacc) @ outW + outb
// Mz = Wz@LzW[0:32,:], cz = bz@LzW[0:32,:]+Lzb (folded on device each call).
//
// Dtype is probed ON DEVICE: x ~ N(0,1). If the buffer is fp32, the low u16
// of each float is random mantissa bits -> bf16-exponent field uniform ->
// ~84% "extreme". If genuinely bf16, ~0% extreme. flag=1 => fp32 buffers.

#define NN 50000
#define NE 800000

typedef unsigned short u16;

__device__ __forceinline__ float b2f(u16 v) {
    union { unsigned int u; float f; } c; c.u = ((unsigned int)v) << 16; return c.f;
}
__device__ __forceinline__ u16 f2b(float f) {
    union { float f; unsigned int u; } c; c.f = f;
    unsigned int u = c.u;
    return (u16)((u + 0x7fffu + ((u >> 16) & 1u)) >> 16);   // RNE
}
__device__ __forceinline__ float ldf(const void* p, long long i, int f32) {
    return f32 ? ((const float*)p)[i] : b2f(((const u16*)p)[i]);
}

// ---- workspace layout (fp32 offsets) ----
#define OFF_FLAG  0
#define OFF_DEG   64
#define OFF_DINV  50112
#define OFF_XAGG  100160
#define OFF_PAR   1700160   // Mz[128] Mh[128] cz[32] ch[32] p[8] oW[256] ob[8]

__global__ void k_probe(const void* x, int* flag) {
    __shared__ int cnt;
    int t = threadIdx.x;
    if (t == 0) cnt = 0;
    __syncthreads();
    // sample even u16 indices (= low halves if fp32)
    u16 v = ((const u16*)x)[2 * t];
    int e = (v >> 7) & 0xFF;
    if (e > 140 || e < 100) atomicAdd(&cnt, 1);
    __syncthreads();
    if (t == 0) *flag = (cnt >= 64) ? 1 : 0;
}

__global__ void k_deg_init(float* deg) {
    int i = blockIdx.x * 256 + threadIdx.x;
    if (i < NN) deg[i] = 1.0f;                 // self-loop
}

__global__ void k_deg_edges(const int* ei, float* deg) {
    int e = blockIdx.x * 256 + threadIdx.x;
    if (e < NE) atomicAdd(&deg[ei[NE + e]], 1.0f);   // dst in-degree
}

__global__ void k_dinv(const float* deg, float* dinv) {
    int i = blockIdx.x * 256 + threadIdx.x;
    if (i < NN) dinv[i] = rsqrtf(deg[i]);
}

// Xagg init with self-loop contribution: Xagg[n][k] = dinv[n]^2 * x[n][k]
__global__ void k_self(const void* x, const float* dinv, float* xagg, const int* flag) {
    int g = blockIdx.x * 256 + threadIdx.x;
    if (g >= NN * 32) return;
    int f32 = *flag;
    int n = g >> 5;
    float d = dinv[n];
    xagg[g] = d * d * ldf(x, g, f32);
}

// edge scatter: 32 lanes per edge, lane k handles feature k
__global__ void k_edges(const void* x, const int* ei, const float* dinv, float* xagg,
                        const int* flag) {
    long long g = (long long)blockIdx.x * 256 + threadIdx.x;
    if (g >= (long long)NE * 32) return;
    int f32 = *flag;
    int e = (int)(g >> 5), k = (int)(g & 31);
    int s = ei[e], d = ei[NE + e];
    float w = dinv[s] * dinv[d];
    atomicAdd(&xagg[d * 32 + k], w * ldf(x, (long long)s * 32 + k, f32));
}

__global__ void k_params(const void* Wz, const void* bz, const void* Wh, const void* bh,
                         const void* LzW, const void* Lzb, const void* LhW, const void* Lhb,
                         const void* att, const void* outW, const void* outb,
                         float* pp, const int* flag) {
    int t = threadIdx.x;
    int f32 = *flag;
    if (t < 128) {
        int f = t >> 5, k = t & 31;
        float mz = 0.f, mh = 0.f;
        for (int j = 0; j < 32; ++j) {
            mz += ldf(Wz, f * 32 + j, f32) * ldf(LzW, j * 32 + k, f32);
            mh += ldf(Wh, f * 32 + j, f32) * ldf(LhW, j * 32 + k, f32);
        }
        pp[t] = mz; pp[128 + t] = mh;
    }
    if (t < 32) {
        float cz = ldf(Lzb, t, f32), ch = ldf(Lhb, t, f32);
        for (int j = 0; j < 32; ++j) {
            cz += ldf(bz, j, f32) * ldf(LzW, j * 32 + t, f32);
            ch += ldf(bh, j, f32) * ldf(LhW, j * 32 + t, f32);
        }
        pp[256 + t] = cz; pp[288 + t] = ch;
    }
    if (t < 8) {
        float m = -1e30f;
        for (int j = 0; j < 8; ++j) m = fmaxf(m, ldf(att, j, f32));
        float s = 0.f;
        for (int j = 0; j < 8; ++j) s += __expf(ldf(att, j, f32) - m);
        pp[320 + t] = __expf(ldf(att, t, f32) - m) / s;
        pp[584 + t] = ldf(outb, t, f32);
    }
    if (t < 256) pp[328 + t] = ldf(outW, t, f32);
}

__global__ __launch_bounds__(256) void k_nodes(const float* xagg, const float* pp,
                                               void* out, const int* flag) {
    __shared__ float sMz[128], sMh[128], scz[32], sch[32], sp[8], soW[256], sob[8];
    __shared__ int sflag;
    int t = threadIdx.x;
    if (t < 128) { sMz[t] = pp[t]; sMh[t] = pp[128 + t]; }
    if (t < 32)  { scz[t] = pp[256 + t]; sch[t] = pp[288 + t]; }
    if (t < 8)   { sp[t] = pp[320 + t]; sob[t] = pp[584 + t]; }
    if (t == 0)  { sflag = *flag; }
    soW[t] = pp[328 + t];
    __syncthreads();

    int n = blockIdx.x * 256 + t;
    if (n >= NN) return;

    float u[32];
    const float* xr = xagg + n * 32;
#pragma unroll
    for (int k = 0; k < 32; ++k) u[k] = xr[k];

    float hacc[32];
#pragma unroll
    for (int k = 0; k < 32; ++k) hacc[k] = 0.f;

    for (int tp = 0; tp < 8; ++tp) {
        float u0 = u[tp], u1 = u[8 + tp], u2 = u[16 + tp], u3 = u[24 + tp];
        float pt = sp[tp];
#pragma unroll
        for (int k = 0; k < 32; ++k) {
            float az = scz[k] + u0 * sMz[k] + u1 * sMz[32 + k] + u2 * sMz[64 + k] + u3 * sMz[96 + k];
            float ah = sch[k] + u0 * sMh[k] + u1 * sMh[32 + k] + u2 * sMh[64 + k] + u3 * sMh[96 + k];
            float z  = 1.f / (1.f + __expf(-az));
            float th = 1.f - 2.f / (__expf(2.f * ah) + 1.f);   // tanh, inf-safe
            hacc[k] += pt * (1.f - z) * th;
        }
    }
#pragma unroll
    for (int k = 0; k < 32; ++k) hacc[k] = fmaxf(hacc[k], 0.f);

    float res[8];
#pragma unroll
    for (int o = 0; o < 8; ++o) {
        float r = sob[o];
#pragma unroll
        for (int k = 0; k < 32; ++k) r += hacc[k] * soW[k * 8 + o];
        res[o] = r;
    }

    if (sflag) {
        float4 a = make_float4(res[0], res[1], res[2], res[3]);
        float4 b = make_float4(res[4], res[5], res[6], res[7]);
        ((float4*)out)[2 * n] = a;
        ((float4*)out)[2 * n + 1] = b;
    } else {
        uint4 pack;
        pack.x = (unsigned)f2b(res[0]) | ((unsigned)f2b(res[1]) << 16);
        pack.y = (unsigned)f2b(res[2]) | ((unsigned)f2b(res[3]) << 16);
        pack.z = (unsigned)f2b(res[4]) | ((unsigned)f2b(res[5]) << 16);
        pack.w = (unsigned)f2b(res[6]) | ((unsigned)f2b(res[7]) << 16);
        ((uint4*)out)[n] = pack;
    }
}

extern "C" void kernel_launch(void* const* d_in, const int* in_sizes, int n_in,
                              void* d_out, int out_size, void* d_ws, size_t ws_size,
                              hipStream_t stream) {
    const void* x    = d_in[0];
    const int*  ei   = (const int*)d_in[1];
    const void* Wz   = d_in[2];
    const void* bz   = d_in[3];
    // d_in[4], d_in[5] = Wr, br  (dead: H0==0)
    const void* Wh   = d_in[6];
    const void* bh   = d_in[7];
    const void* LzW  = d_in[8];
    const void* Lzb  = d_in[9];
    // d_in[10], d_in[11] = LrW, Lrb (dead)
    const void* LhW  = d_in[12];
    const void* Lhb  = d_in[13];
    const void* att  = d_in[14];
    const void* outW = d_in[15];
    const void* outb = d_in[16];

    float* W = (float*)d_ws;
    int*   flag = (int*)(W + OFF_FLAG);
    float* deg  = W + OFF_DEG;
    float* dinv = W + OFF_DINV;
    float* xagg = W + OFF_XAGG;
    float* pp   = W + OFF_PAR;

    k_probe<<<1, 256, 0, stream>>>(x, flag);
    k_params<<<1, 256, 0, stream>>>(Wz, bz, Wh, bh, LzW, Lzb, LhW, Lhb, att, outW, outb, pp, flag);
    k_deg_init<<<(NN + 255) / 256, 256, 0, stream>>>(deg);
    k_deg_edges<<<(NE + 255) / 256, 256, 0, stream>>>(ei, deg);
    k_dinv<<<(NN + 255) / 256, 256, 0, stream>>>(deg, dinv);
    k_self<<<(NN * 32 + 255) / 256, 256, 0, stream>>>(x, dinv, xagg, flag);
    k_edges<<<(int)(((long long)NE * 32 + 255) / 256), 256, 0, stream>>>(x, ei, dinv, xagg, flag);
    k_nodes<<<(NN + 255) / 256, 256, 0, stream>>>(xagg, pp, d_out, flag);
}

// Round 3
// 263.080 us; speedup vs baseline: 1.0702x; 1.0702x over previous
//
#include <hip/hip_runtime.h>
#include <hip/hip_bf16.h>

// A3TGCN reduced form (H0==0 each period => R-gate dead, periods independent):
//   Xagg = A_hat @ x   (CSR gather, no fp32 scatter atomics)
//   per node/period: Z=sigmoid(u@Mz+cz), T=tanh(u@Mh+ch), Hacc += p_t*(1-Z)*T
//   out = relu(Hacc) @ outW + outb
// Pipeline (5 dispatches + 1 memset):
//   memset(cnt=0) ; k_count (deg count + dtype probe + param fold, fused)
//   k_scan (1-block exclusive scan -> rowptr/cursor, dinv=rsqrt(deg+1))
//   k_fill (bucket CSR: cursor atomics)
//   k_gather (per-node wave: gather + self-loop + GRU dense + out, fused)

#define NN 50000
#define NE 800000

typedef unsigned short u16;

__device__ __forceinline__ float b2f(u16 v) {
    union { unsigned int u; float f; } c; c.u = ((unsigned int)v) << 16; return c.f;
}
__device__ __forceinline__ u16 f2b(float f) {
    union { float f; unsigned int u; } c; c.f = f;
    unsigned int u = c.u;
    return (u16)((u + 0x7fffu + ((u >> 16) & 1u)) >> 16);   // RNE
}
__device__ __forceinline__ float ldf(const void* p, int i, int f32) {
    return f32 ? ((const float*)p)[i] : b2f(((const u16*)p)[i]);
}

// ---- workspace layout (4-byte word offsets; base is 256B-aligned) ----
#define OFF_FLAG    0
#define OFF_CNT     64        // int[50000]
#define OFF_ROWPTR  50176     // int[50001]
#define OFF_CURSOR  100352    // int[50000]
#define OFF_DINV    150528    // float[50000]
#define OFF_CSR     200704    // int[800000]
#define OFF_PAR     1000704   // Mz[128] Mh[128] cz[32] ch[32] p[8] oW@328[256] ob@584[8]

// deg count over edges; block 0 additionally probes dtype + folds params.
__global__ __launch_bounds__(256) void k_count(const int* ei, int* cnt, const void* x,
        const void* Wz, const void* bz, const void* Wh, const void* bh,
        const void* LzW, const void* Lzb, const void* LhW, const void* Lhb,
        const void* att, const void* outW, const void* outb,
        float* pp, int* flag) {
    int t = threadIdx.x;
    int e = blockIdx.x * 256 + t;
    if (e < NE) atomicAdd(&cnt[ei[NE + e]], 1);
    if (blockIdx.x != 0) return;

    // dtype probe: if fp32, low u16 halves have random bf16-exponent bits
    __shared__ int scnt;
    if (t == 0) scnt = 0;
    __syncthreads();
    u16 v = ((const u16*)x)[2 * t];
    int ex = (v >> 7) & 0xFF;
    if (ex > 140 || ex < 100) atomicAdd(&scnt, 1);
    __syncthreads();
    int f32 = (scnt >= 64) ? 1 : 0;
    if (t == 0) *flag = f32;

    if (t < 128) {
        int f = t >> 5, k = t & 31;
        float mz = 0.f, mh = 0.f;
        for (int j = 0; j < 32; ++j) {
            mz += ldf(Wz, f * 32 + j, f32) * ldf(LzW, j * 32 + k, f32);
            mh += ldf(Wh, f * 32 + j, f32) * ldf(LhW, j * 32 + k, f32);
        }
        pp[t] = mz; pp[128 + t] = mh;
    }
    if (t < 32) {
        float cz = ldf(Lzb, t, f32), ch = ldf(Lhb, t, f32);
        for (int j = 0; j < 32; ++j) {
            cz += ldf(bz, j, f32) * ldf(LzW, j * 32 + t, f32);
            ch += ldf(bh, j, f32) * ldf(LhW, j * 32 + t, f32);
        }
        pp[256 + t] = cz; pp[288 + t] = ch;
    }
    if (t < 8) {
        float m = -1e30f;
        for (int j = 0; j < 8; ++j) m = fmaxf(m, ldf(att, j, f32));
        float s = 0.f;
        for (int j = 0; j < 8; ++j) s += __expf(ldf(att, j, f32) - m);
        pp[320 + t] = __expf(ldf(att, t, f32) - m) / s;
        pp[584 + t] = ldf(outb, t, f32);
    }
    pp[328 + t] = ldf(outW, t, f32);
}

// single-block exclusive scan of cnt -> rowptr & cursor; dinv = rsqrt(cnt+1).
// 1024 threads x 4 elements/chunk (NN % 4 == 0).
__global__ __launch_bounds__(1024) void k_scan(const int* cnt, int* rowptr, int* cursor,
                                               float* dinv) {
    __shared__ int wsum[16];
    int t = threadIdx.x;
    int carry = 0;
    for (int base = 0; base < NN; base += 4096) {
        int i = base + t * 4;
        int4 v = make_int4(0, 0, 0, 0);
        if (i < NN) v = ((const int4*)cnt)[i >> 2];
        int s01 = v.x + v.y;
        int local = s01 + v.z + v.w;
        int xs = local;
        for (int d = 1; d < 64; d <<= 1) {
            int y = __shfl_up(xs, d, 64);
            if ((t & 63) >= d) xs += y;
        }
        if ((t & 63) == 63) wsum[t >> 6] = xs;
        __syncthreads();
        if (t < 16) {
            int w = wsum[t];
            for (int d = 1; d < 16; d <<= 1) {
                int y = __shfl_up(w, d, 64);
                if (t >= d) w += y;
            }
            wsum[t] = w;
        }
        __syncthreads();
        int off = carry + ((t >> 6) ? wsum[(t >> 6) - 1] : 0) + (xs - local);
        if (i < NN) {
            int4 rp;
            rp.x = off;
            rp.y = off + v.x;
            rp.z = off + s01;
            rp.w = off + s01 + v.z;
            ((int4*)rowptr)[i >> 2] = rp;
            ((int4*)cursor)[i >> 2] = rp;
            float4 dv;
            dv.x = rsqrtf((float)(v.x + 1));
            dv.y = rsqrtf((float)(v.y + 1));
            dv.z = rsqrtf((float)(v.z + 1));
            dv.w = rsqrtf((float)(v.w + 1));
            ((float4*)dinv)[i >> 2] = dv;
        }
        carry += wsum[15];
        __syncthreads();
    }
    if (t == 0) rowptr[NN] = carry;
}

__global__ __launch_bounds__(256) void k_fill(const int* ei, int* cursor, int* csr) {
    int e = blockIdx.x * 256 + threadIdx.x;
    if (e < NE) {
        int s = ei[e], d = ei[NE + e];
        int pos = atomicAdd(&cursor[d], 1);
        csr[pos] = s;
    }
}

// one wave per node: 64 lanes = 2 edges x 32 features; fused self-loop +
// GRU dense (shfl broadcasts) + output projection (LDS transpose).
__global__ __launch_bounds__(256) void k_gather(const void* x, const int* rowptr,
        const int* csr, const float* dinv, const float* pp, void* out, const int* flag) {
    __shared__ float sMz[128], sMh[128], scz[32], sch[32], sp[8], soW[256], sob[8];
    __shared__ float st[4][32];
    __shared__ int sflag;
    int t = threadIdx.x;
    if (t < 128) { sMz[t] = pp[t]; sMh[t] = pp[128 + t]; }
    if (t < 32)  { scz[t] = pp[256 + t]; sch[t] = pp[288 + t]; }
    if (t < 8)   { sp[t] = pp[320 + t]; sob[t] = pp[584 + t]; }
    if (t == 0)  sflag = *flag;
    soW[t] = pp[328 + t];
    __syncthreads();

    int f32 = sflag;
    int wv = t >> 6, ln = t & 63, k = ln & 31, half = ln >> 5;
    int n = blockIdx.x * 4 + wv;              // grid 12500 * 4 == NN exactly
    int e0 = rowptr[n], e1 = rowptr[n + 1];
    float dd = dinv[n];

    float acc = 0.f;
    for (int e = e0 + half; e < e1; e += 2) {
        int s = csr[e];
        acc += dinv[s] * ldf(x, s * 32 + k, f32);
    }
    acc *= dd;
    acc += __shfl_xor(acc, 32, 64);           // combine the two edge-halves
    acc += dd * dd * ldf(x, n * 32 + k, f32); // self-loop

    float hacc = 0.f;
#pragma unroll
    for (int tp = 0; tp < 8; ++tp) {
        float u0 = __shfl(acc, tp, 64);
        float u1 = __shfl(acc, 8 + tp, 64);
        float u2 = __shfl(acc, 16 + tp, 64);
        float u3 = __shfl(acc, 24 + tp, 64);
        float az = scz[k] + u0 * sMz[k] + u1 * sMz[32 + k] + u2 * sMz[64 + k] + u3 * sMz[96 + k];
        float ah = sch[k] + u0 * sMh[k] + u1 * sMh[32 + k] + u2 * sMh[64 + k] + u3 * sMh[96 + k];
        float z  = 1.f / (1.f + __expf(-az));
        float th = 1.f - 2.f / (__expf(2.f * ah) + 1.f);   // tanh, inf-safe
        hacc += sp[tp] * (1.f - z) * th;
    }
    hacc = fmaxf(hacc, 0.f);

    if (half == 0) st[wv][k] = hacc;
    __syncthreads();
    if (ln < 8) {
        float r = sob[ln];
#pragma unroll
        for (int j = 0; j < 32; ++j) r += st[wv][j] * soW[j * 8 + ln];
        if (f32) ((float*)out)[n * 8 + ln] = r;
        else     ((u16*)out)[n * 8 + ln] = f2b(r);
    }
}

extern "C" void kernel_launch(void* const* d_in, const int* in_sizes, int n_in,
                              void* d_out, int out_size, void* d_ws, size_t ws_size,
                              hipStream_t stream) {
    const void* x    = d_in[0];
    const int*  ei   = (const int*)d_in[1];
    const void* Wz   = d_in[2];
    const void* bz   = d_in[3];
    // d_in[4], d_in[5] = Wr, br  (dead: H0==0)
    const void* Wh   = d_in[6];
    const void* bh   = d_in[7];
    const void* LzW  = d_in[8];
    const void* Lzb  = d_in[9];
    // d_in[10], d_in[11] = LrW, Lrb (dead)
    const void* LhW  = d_in[12];
    const void* Lhb  = d_in[13];
    const void* att  = d_in[14];
    const void* outW = d_in[15];
    const void* outb = d_in[16];

    float* W = (float*)d_ws;
    int*   flag   = (int*)(W + OFF_FLAG);
    int*   cnt    = (int*)(W + OFF_CNT);
    int*   rowptr = (int*)(W + OFF_ROWPTR);
    int*   cursor = (int*)(W + OFF_CURSOR);
    float* dinv   = W + OFF_DINV;
    int*   csr    = (int*)(W + OFF_CSR);
    float* pp     = W + OFF_PAR;

    hipMemsetAsync(cnt, 0, NN * sizeof(int), stream);
    k_count<<<(NE + 255) / 256, 256, 0, stream>>>(ei, cnt, x, Wz, bz, Wh, bh,
            LzW, Lzb, LhW, Lhb, att, outW, outb, pp, flag);
    k_scan<<<1, 1024, 0, stream>>>(cnt, rowptr, cursor, dinv);
    k_fill<<<(NE + 255) / 256, 256, 0, stream>>>(ei, cursor, csr);
    k_gather<<<NN / 4, 256, 0, stream>>>(x, rowptr, csr, dinv, pp, d_out, flag);
}